// Round 4
// baseline (1076.836 us; speedup 1.0000x reference)
//
#include <hip/hip_runtime.h>

#define N_NODES 100000
#define N_EDGES 1600000
#define D 128
#define NLAYER 3
#define NSLOT 32

// bucket sort params
#define NBKT 98          // ceil(100000 / 1024) node-buckets of 1024
#define EPB 4096         // edges per block in phase A
#define BCAP 96          // LDS per-bucket capacity (mean ~42/block)

typedef __bf16 bf16x8 __attribute__((ext_vector_type(8)));
typedef float f32x4 __attribute__((ext_vector_type(4)));

__device__ inline ushort f2b(float f) {
    union { float f; unsigned u; } v; v.f = f;
    unsigned u = v.u;
    return (ushort)((u + 0x7FFFu + ((u >> 16) & 1u)) >> 16);  // RNE
}
__device__ inline float b2f_lo(unsigned u) {
    union { unsigned u; float f; } v; v.u = u << 16; return v.f;
}
__device__ inline float b2f_hi(unsigned u) {
    union { unsigned u; float f; } v; v.u = u & 0xFFFF0000u; return v.f;
}

// ---------------------------------------------------------------- utility
__global__ void k_zero_i32(int* __restrict__ p, int n) {
    int i = blockIdx.x * blockDim.x + threadIdx.x;
    if (i < n) p[i] = 0;
}

// x fp32 -> packed bf16 (layer-0 agg input): halves layer-0 gather bytes
__global__ __launch_bounds__(256)
void k_x2b(const float* __restrict__ x, unsigned* __restrict__ out, int n4) {
    int i = blockIdx.x * 256 + threadIdx.x;  // float4 index
    if (i >= n4) return;
    float4 v = ((const float4*)x)[i];
    uint2 o;
    o.x = (unsigned)f2b(v.x) | ((unsigned)f2b(v.y) << 16);
    o.y = (unsigned)f2b(v.z) | ((unsigned)f2b(v.w) << 16);
    ((uint2*)out)[i] = o;
}

// ---------------------------------------------------------------- CSR build
__global__ void k_hist(const int* __restrict__ dst, int* __restrict__ deg, int e) {
    int i = blockIdx.x * blockDim.x + threadIdx.x;
    if (i < e) atomicAdd(&deg[dst[i]], 1);
}

__global__ void k_scan_partial(const int* __restrict__ deg, int* __restrict__ bsum, int n) {
    __shared__ int sd[256];
    int tid  = threadIdx.x;
    int base = blockIdx.x * 1024 + tid * 4;
    int s = 0;
    #pragma unroll
    for (int j = 0; j < 4; ++j) {
        int idx = base + j;
        if (idx < n) s += deg[idx];
    }
    sd[tid] = s;
    __syncthreads();
    for (int o = 128; o > 0; o >>= 1) {
        if (tid < o) sd[tid] += sd[tid + o];
        __syncthreads();
    }
    if (tid == 0) bsum[blockIdx.x] = sd[0];
}

__global__ void k_scan_top(int* __restrict__ bsum, int nb) {
    __shared__ int sd[128];
    int tid = threadIdx.x;
    int v = (tid < nb) ? bsum[tid] : 0;
    sd[tid] = v;
    __syncthreads();
    int tot = v;
    for (int o = 1; o < 128; o <<= 1) {
        int t = (tid >= o) ? sd[tid - o] : 0;
        __syncthreads();
        sd[tid] += t;
        __syncthreads();
    }
    if (tid < nb) bsum[tid] = sd[tid] - tot;  // exclusive
}

__global__ void k_scan_final(const int* __restrict__ deg, const int* __restrict__ bofs,
                             int* __restrict__ offs, int* __restrict__ cursor,
                             int* __restrict__ bcur, int n) {
    __shared__ int sd[256];
    int tid  = threadIdx.x;
    int base = blockIdx.x * 1024 + tid * 4;
    int v[4];
    int s = 0;
    #pragma unroll
    for (int j = 0; j < 4; ++j) {
        int idx = base + j;
        v[j] = (idx < n) ? deg[idx] : 0;
        s += v[j];
    }
    sd[tid] = s;
    __syncthreads();
    int own = s;
    for (int o = 1; o < 256; o <<= 1) {
        int t = (tid >= o) ? sd[tid - o] : 0;
        __syncthreads();
        sd[tid] += t;
        __syncthreads();
    }
    int excl = sd[tid] - own + bofs[blockIdx.x];
    #pragma unroll
    for (int j = 0; j < 4; ++j) {
        int idx = base + j;
        if (idx < n) {
            offs[idx] = excl; cursor[idx] = excl;
            if ((idx & 1023) == 0) bcur[idx >> 10] = excl;  // bucket region start
        }
        excl += v[j];
    }
}

// ---------------------------------------------------------------- bucketed edge sort
__global__ __launch_bounds__(256)
void k_bucket(const int* __restrict__ src, const int* __restrict__ dst,
              int* __restrict__ bcur, unsigned* __restrict__ staged, int e) {
    __shared__ unsigned lstage[NBKT * BCAP];
    __shared__ int lcur[NBKT];
    __shared__ int lbase[NBKT];
    int tid = threadIdx.x;
    for (int b = tid; b < NBKT; b += 256) lcur[b] = 0;
    __syncthreads();
    int base = blockIdx.x * EPB;
    for (int k = 0; k < EPB / 256; ++k) {
        int eid = base + k * 256 + tid;
        if (eid < e) {
            int d = dst[eid];
            int s = src[eid];
            int b = d >> 10;
            unsigned packed = ((unsigned)(d & 1023) << 17) | (unsigned)s;
            int p = atomicAdd(&lcur[b], 1);
            if (p < BCAP) {
                lstage[b * BCAP + p] = packed;
            } else {  // overflow fallback (statistically never: cap = 2.3x mean)
                int gp = atomicAdd(&bcur[b], 1);
                staged[gp] = packed;
            }
        }
    }
    __syncthreads();
    if (tid < NBKT) {
        int cnt = min(lcur[tid], BCAP);
        lbase[tid] = atomicAdd(&bcur[tid], cnt);
        lcur[tid] = cnt;
    }
    __syncthreads();
    int wave = tid >> 6, lane = tid & 63;
    for (int b = wave; b < NBKT; b += 4) {
        int cnt = lcur[b], gb = lbase[b];
        for (int j = lane; j < cnt; j += 64)
            staged[gb + j] = lstage[b * BCAP + j];
    }
}

__global__ __launch_bounds__(1024)
void k_place(const unsigned* __restrict__ staged, const int* __restrict__ offs,
             int* __restrict__ cursor, int* __restrict__ csrc) {
    int b = blockIdx.x;
    int start = offs[b << 10];
    int end = (b == NBKT - 1) ? N_EDGES : offs[(b + 1) << 10];
    int nodebase = b << 10;
    for (int i = start + blockIdx.y * 1024 + threadIdx.x; i < end; i += 2048) {
        unsigned p = staged[i];
        int s = (int)(p & 0x1FFFFu);
        int rel = (int)(p >> 17);
        int pos = atomicAdd(&cursor[nodebase + rel], 1);
        csrc[pos] = s;
    }
}

// ---------------------------------------------------------------- gather helper
template <bool AFF>
__device__ inline void acc8(float* a, uint4 u, const float* sc, const float* sh) {
    float v[8];
    v[0] = b2f_lo(u.x); v[1] = b2f_hi(u.x);
    v[2] = b2f_lo(u.y); v[3] = b2f_hi(u.y);
    v[4] = b2f_lo(u.z); v[5] = b2f_hi(u.z);
    v[6] = b2f_lo(u.w); v[7] = b2f_hi(u.w);
    #pragma unroll
    for (int j = 0; j < 8; ++j) {
        float t = v[j];
        if (AFF) {
            t = t * sc[j] + sh[j];
            t = t > 0.f ? t : 0.f;
        }
        a[j] += t;
    }
}

// ---------------------------------------------------------------- fused agg + GEMM1
// Per block: aggregate 128 nodes (with optional BN2+relu of prev layer fused into
// gathered values) -> bf16 A-tile in LDS -> MFMA x W1 (+bias1) -> z1 + col stats.
template <bool AFF>
__global__ __launch_bounds__(256)
void k_agg_gemm(const unsigned* __restrict__ h, const int* __restrict__ offs,
                const int* __restrict__ deg, const int* __restrict__ csrc,
                const float* __restrict__ stats_prev, const float* __restrict__ gamma_p,
                const float* __restrict__ beta_p,
                const ushort* __restrict__ Wt, const float* __restrict__ bias,
                ushort* __restrict__ C, float* __restrict__ stats_out,
                int n, float inv_n) {
    __shared__ ushort A_lds[128 * 136];   // row stride 136 ushorts = 272 B
    __shared__ float sc_lds[128], sh_lds[128];

    int tid = threadIdx.x;
    if (AFF) {
        if (tid < 128) {
            float s = 0.f, qq = 0.f;
            for (int sl = 0; sl < NSLOT; ++sl) {
                s  += stats_prev[sl * 256 + tid];
                qq += stats_prev[sl * 256 + 128 + tid];
            }
            float mu  = s * inv_n;
            float var = qq * inv_n - mu * mu;
            var = var < 0.f ? 0.f : var;
            float rs = rsqrtf(var + 1e-5f);
            float sc = gamma_p[tid] * rs;
            sc_lds[tid] = sc;
            sh_lds[tid] = beta_p[tid] - mu * sc;
        }
        __syncthreads();
    }

    int lane = tid & 63, wv = tid >> 6;
    int q  = lane >> 4;   // neighbor stream
    int sl = lane & 15;   // 16B segment (cols 8sl..8sl+7)
    const uint4* hp = (const uint4*)h;
    float sc[8], sh[8];
    if (AFF) {
        #pragma unroll
        for (int j = 0; j < 8; ++j) { sc[j] = sc_lds[sl * 8 + j]; sh[j] = sh_lds[sl * 8 + j]; }
    }

    int rowbase = blockIdx.x * 128 + wv * 32;

    // ---- gather phase: 32 nodes per wave ----
    for (int r = 0; r < 32; ++r) {
        int node = rowbase + r;
        float a[8];
        #pragma unroll
        for (int j = 0; j < 8; ++j) a[j] = 0.f;
        if (node < n) {
            if (q == 0) acc8<AFF>(a, hp[(size_t)node * 16 + sl], sc, sh);
            int s = offs[node], d = deg[node];
            for (int c = 0; c < d; c += 64) {
                int m = min(64, d - c);
                int myi = (lane < m) ? csrc[s + c + lane] : 0;
                int g4 = m >> 2;
                int g = 0;
                for (; g + 4 <= g4; g += 4) {
                    int n0 = __shfl(myi, 4 * g + 0 + q);
                    int n1 = __shfl(myi, 4 * g + 4 + q);
                    int n2 = __shfl(myi, 4 * g + 8 + q);
                    int n3 = __shfl(myi, 4 * g + 12 + q);
                    uint4 u0 = hp[(size_t)n0 * 16 + sl];
                    uint4 u1 = hp[(size_t)n1 * 16 + sl];
                    uint4 u2 = hp[(size_t)n2 * 16 + sl];
                    uint4 u3 = hp[(size_t)n3 * 16 + sl];
                    acc8<AFF>(a, u0, sc, sh);
                    acc8<AFF>(a, u1, sc, sh);
                    acc8<AFF>(a, u2, sc, sh);
                    acc8<AFF>(a, u3, sc, sh);
                }
                for (; g < g4; ++g) {
                    int nb = __shfl(myi, 4 * g + q);
                    acc8<AFF>(a, hp[(size_t)nb * 16 + sl], sc, sh);
                }
                int rem = m & 3;
                if (rem) {
                    int j = 4 * g4 + q;
                    int nb = __shfl(myi, j < m ? j : 0);  // convergent shfl
                    if (q < rem) acc8<AFF>(a, hp[(size_t)nb * 16 + sl], sc, sh);
                }
            }
            #pragma unroll
            for (int j = 0; j < 8; ++j) {
                a[j] += __shfl_xor(a[j], 16);
                a[j] += __shfl_xor(a[j], 32);
            }
        }
        if (q == 0) {
            uint4 o;
            o.x = (unsigned)f2b(a[0]) | ((unsigned)f2b(a[1]) << 16);
            o.y = (unsigned)f2b(a[2]) | ((unsigned)f2b(a[3]) << 16);
            o.z = (unsigned)f2b(a[4]) | ((unsigned)f2b(a[5]) << 16);
            o.w = (unsigned)f2b(a[6]) | ((unsigned)f2b(a[7]) << 16);
            *(uint4*)&A_lds[(wv * 32 + r) * 136 + sl * 8] = o;
        }
    }
    __syncthreads();

    // ---- GEMM phase: A from LDS, B (Wt) from global (L2-resident 32 KB) ----
    int m16 = lane & 15;
    int kq  = lane >> 4;
    f32x4 acc0[8], acc1[8];
    #pragma unroll
    for (int t = 0; t < 8; ++t) {
        acc0[t] = (f32x4){0.f, 0.f, 0.f, 0.f};
        acc1[t] = (f32x4){0.f, 0.f, 0.f, 0.f};
    }
    #pragma unroll 1
    for (int ks = 0; ks < 4; ++ks) {
        int kb = ks * 32 + kq * 8;
        bf16x8 a0 = *(const bf16x8*)&A_lds[(wv * 32 + m16) * 136 + kb];
        bf16x8 a1 = *(const bf16x8*)&A_lds[(wv * 32 + 16 + m16) * 136 + kb];
        #pragma unroll
        for (int t = 0; t < 8; ++t) {
            bf16x8 b = *(const bf16x8*)&Wt[(size_t)(t * 16 + m16) * D + kb];
            acc0[t] = __builtin_amdgcn_mfma_f32_16x16x32_bf16(a0, b, acc0[t], 0, 0, 0);
            acc1[t] = __builtin_amdgcn_mfma_f32_16x16x32_bf16(a1, b, acc1[t], 0, 0, 0);
        }
    }

    // epilogue: bias, bf16 store, fused column stats
    int slot = blockIdx.x & (NSLOT - 1);
    #pragma unroll
    for (int t = 0; t < 8; ++t) {
        int col = t * 16 + m16;
        float bz = bias[col];
        float s = 0.f, qv = 0.f;
        #pragma unroll
        for (int mt = 0; mt < 2; ++mt) {
            f32x4 v4 = mt ? acc1[t] : acc0[t];
            #pragma unroll
            for (int rr = 0; rr < 4; ++rr) {
                int row = rowbase + mt * 16 + kq * 4 + rr;
                if (row < n) {
                    float v = v4[rr] + bz;
                    C[(size_t)row * D + col] = f2b(v);
                    s += v; qv += v * v;
                }
            }
        }
        s += __shfl_xor(s, 16); qv += __shfl_xor(qv, 16);
        s += __shfl_xor(s, 32); qv += __shfl_xor(qv, 32);
        if (kq == 0) {
            atomicAdd(&stats_out[slot * 256 + col], s);
            atomicAdd(&stats_out[slot * 256 + 128 + col], qv);
        }
    }
}

// ---------------------------------------------------------------- weight prep
// W fp32 [3][k=128][n=128] -> Wt bf16 [3][n=128][k=128]
__global__ void k_wprep(const float* __restrict__ W, ushort* __restrict__ Wt) {
    int m = blockIdx.y, nn = blockIdx.x, k = threadIdx.x;
    float v = W[(m * D + k) * D + nn];
    Wt[(m * D + nn) * D + k] = f2b(v);
}

// ---------------------------------------------------------------- GEMM2 (BN1+relu fused in A-load)
__global__ __launch_bounds__(256)
void k_gemm2(const ushort* __restrict__ A, const ushort* __restrict__ Wt,
             const float* __restrict__ bias,
             const float* __restrict__ stats_in, const float* __restrict__ gamma,
             const float* __restrict__ beta,
             ushort* __restrict__ C, float* __restrict__ stats_out,
             int n, float inv_n) {
    __shared__ float sc_lds[128], sh_lds[128];
    int tid = threadIdx.x;
    if (tid < 128) {
        float s = 0.f, qq = 0.f;
        for (int sl = 0; sl < NSLOT; ++sl) {
            s  += stats_in[sl * 256 + tid];
            qq += stats_in[sl * 256 + 128 + tid];
        }
        float mu  = s * inv_n;
        float var = qq * inv_n - mu * mu;
        var = var < 0.f ? 0.f : var;
        float rs = rsqrtf(var + 1e-5f);
        float sc = gamma[tid] * rs;
        sc_lds[tid] = sc;
        sh_lds[tid] = beta[tid] - mu * sc;
    }
    __syncthreads();

    int wv   = tid >> 6;
    int lane = tid & 63;
    int m16  = lane & 15;
    int kq   = lane >> 4;
    int rowbase = blockIdx.x * 128 + wv * 32;

    f32x4 acc0[8], acc1[8];
    #pragma unroll
    for (int t = 0; t < 8; ++t) {
        acc0[t] = (f32x4){0.f, 0.f, 0.f, 0.f};
        acc1[t] = (f32x4){0.f, 0.f, 0.f, 0.f};
    }

    #pragma unroll 1
    for (int ks = 0; ks < 4; ++ks) {
        int kb = ks * 32 + kq * 8;
        bf16x8 a0, a1;
        #pragma unroll
        for (int mt = 0; mt < 2; ++mt) {
            int row = rowbase + mt * 16 + m16;
            bf16x8 r;
            if (row < n) {
                unsigned u[4];
                *(uint4*)u = *(const uint4*)&A[(size_t)row * D + kb];
                #pragma unroll
                for (int p = 0; p < 4; ++p) {
                    float lo = b2f_lo(u[p]) * sc_lds[kb + 2 * p] + sh_lds[kb + 2 * p];
                    float hi = b2f_hi(u[p]) * sc_lds[kb + 2 * p + 1] + sh_lds[kb + 2 * p + 1];
                    lo = lo > 0.f ? lo : 0.f;
                    hi = hi > 0.f ? hi : 0.f;
                    r[2 * p] = (__bf16)lo;
                    r[2 * p + 1] = (__bf16)hi;
                }
            } else {
                #pragma unroll
                for (int j = 0; j < 8; ++j) r[j] = (__bf16)0.0f;
            }
            if (mt == 0) a0 = r; else a1 = r;
        }
        #pragma unroll
        for (int t = 0; t < 8; ++t) {
            bf16x8 b = *(const bf16x8*)&Wt[(size_t)(t * 16 + m16) * D + kb];
            acc0[t] = __builtin_amdgcn_mfma_f32_16x16x32_bf16(a0, b, acc0[t], 0, 0, 0);
            acc1[t] = __builtin_amdgcn_mfma_f32_16x16x32_bf16(a1, b, acc1[t], 0, 0, 0);
        }
    }

    int slot = blockIdx.x & (NSLOT - 1);
    #pragma unroll
    for (int t = 0; t < 8; ++t) {
        int col = t * 16 + m16;
        float bz = bias[col];
        float s = 0.f, qv = 0.f;
        #pragma unroll
        for (int mt = 0; mt < 2; ++mt) {
            f32x4 v4 = mt ? acc1[t] : acc0[t];
            #pragma unroll
            for (int rr = 0; rr < 4; ++rr) {
                int row = rowbase + mt * 16 + kq * 4 + rr;
                if (row < n) {
                    float v = v4[rr] + bz;
                    C[(size_t)row * D + col] = f2b(v);
                    s += v; qv += v * v;
                }
            }
        }
        s += __shfl_xor(s, 16); qv += __shfl_xor(qv, 16);
        s += __shfl_xor(s, 32); qv += __shfl_xor(qv, 32);
        if (kq == 0) {
            atomicAdd(&stats_out[slot * 256 + col], s);
            atomicAdd(&stats_out[slot * 256 + 128 + col], qv);
        }
    }
}

// ---------------------------------------------------------------- BN param fold (final only)
__global__ void k_bnparams(const float* __restrict__ stats, const float* __restrict__ gamma,
                           const float* __restrict__ beta, float* __restrict__ scale,
                           float* __restrict__ shift, float inv_n) {
    int c = threadIdx.x;  // 128 threads
    float s = 0.f, q = 0.f;
    for (int sl = 0; sl < NSLOT; ++sl) {
        s += stats[sl * 256 + c];
        q += stats[sl * 256 + 128 + c];
    }
    float mu  = s * inv_n;
    float var = q * inv_n - mu * mu;
    var = var < 0.f ? 0.f : var;
    float rs = rsqrtf(var + 1e-5f);
    float sc = gamma[c] * rs;
    scale[c] = sc;
    shift[c] = beta[c] - mu * sc;
}

// ---------------------------------------------------------------- final BN apply (fp32 out)
__global__ __launch_bounds__(256)
void k_final(const unsigned* __restrict__ z, const float* __restrict__ scale,
             const float* __restrict__ shift, float* __restrict__ outf, int total2) {
    int i = blockIdx.x * 256 + threadIdx.x;  // index of uint2 = 4 bf16
    if (i >= total2) return;
    uint2 u = ((const uint2*)z)[i];
    int c = (i * 4) & (D - 1);
    float4 o;
    o.x = b2f_lo(u.x) * scale[c + 0] + shift[c + 0];
    o.y = b2f_hi(u.x) * scale[c + 1] + shift[c + 1];
    o.z = b2f_lo(u.y) * scale[c + 2] + shift[c + 2];
    o.w = b2f_hi(u.y) * scale[c + 3] + shift[c + 3];
    ((float4*)outf)[i] = o;
}

// ---------------------------------------------------------------- launch
extern "C" void kernel_launch(void* const* d_in, const int* in_sizes, int n_in,
                              void* d_out, int out_size, void* d_ws, size_t ws_size,
                              hipStream_t stream) {
    const float* x   = (const float*)d_in[0];
    const int*   ei  = (const int*)d_in[1];
    const float* W1  = (const float*)d_in[4];
    const float* b1  = (const float*)d_in[5];
    const float* g1  = (const float*)d_in[6];
    const float* be1 = (const float*)d_in[7];
    const float* W2  = (const float*)d_in[8];
    const float* b2  = (const float*)d_in[9];
    const float* g2  = (const float*)d_in[10];
    const float* be2 = (const float*)d_in[11];

    const int* srcI = ei;             // edge_index[0]
    const int* dstI = ei + N_EDGES;   // edge_index[1]

    // workspace layout (~60 MB)
    char* ws = (char*)d_ws;
    unsigned* bufA = (unsigned*)ws; ws += (size_t)N_NODES * 64 * 4 + 65536;
    unsigned* bufB = (unsigned*)ws; ws += (size_t)N_NODES * 64 * 4 + 65536;
    int* csrc    = (int*)ws;   ws += (size_t)N_EDGES * 4;
    int* deg     = (int*)ws;   ws += (size_t)N_NODES * 4;
    int* offs    = (int*)ws;   ws += (size_t)N_NODES * 4;
    int* cursor  = (int*)ws;   ws += (size_t)N_NODES * 4;
    int* bsum    = (int*)ws;   ws += 512;
    int* bcur    = (int*)ws;   ws += 512;
    ushort* Wt1  = (ushort*)ws; ws += 3 * D * D * 2;
    ushort* Wt2  = (ushort*)ws; ws += 3 * D * D * 2;
    float* stats = (float*)ws; ws += 6 * NSLOT * 256 * 4;  // 6 write-once regions
    float* scale2 = (float*)ws; ws += 512;
    float* shift2 = (float*)ws; ws += 512;

    // staging buffer for bucketed edge sort: reuse bufB (dead until x2b)
    unsigned* staged = bufB;

    // ---- weight prep (fp32 -> transposed bf16) ----
    k_wprep<<<dim3(D, 3), D, 0, stream>>>(W1, Wt1);
    k_wprep<<<dim3(D, 3), D, 0, stream>>>(W2, Wt2);

    // ---- CSR build ----
    k_zero_i32<<<(N_NODES + 255) / 256, 256, 0, stream>>>(deg, N_NODES);
    k_hist<<<(N_EDGES + 255) / 256, 256, 0, stream>>>(dstI, deg, N_EDGES);
    int nsb = (N_NODES + 1023) / 1024;  // 98
    k_scan_partial<<<nsb, 256, 0, stream>>>(deg, bsum, N_NODES);
    k_scan_top<<<1, 128, 0, stream>>>(bsum, nsb);
    k_scan_final<<<nsb, 256, 0, stream>>>(deg, bsum, offs, cursor, bcur, N_NODES);
    k_bucket<<<(N_EDGES + EPB - 1) / EPB, 256, 0, stream>>>(srcI, dstI, bcur, staged, N_EDGES);
    k_place<<<dim3(NBKT, 2), 1024, 0, stream>>>(staged, offs, cursor, csrc);

    // x -> bf16 into bufB (staged is dead now)
    k_x2b<<<(N_NODES * 32 + 255) / 256, 256, 0, stream>>>(x, bufB, N_NODES * 32);

    // zero all 6 write-once stats regions (re-zeroed each graph replay)
    k_zero_i32<<<(6 * NSLOT * 256 + 255) / 256, 256, 0, stream>>>((int*)stats, 6 * NSLOT * 256);

    const float inv_n = 1.0f / (float)N_NODES;
    int ngemm = (N_NODES + 127) / 128;  // 782
    int nfin  = (N_NODES * D / 4 + 255) / 256;

    // per layer: bufB (h) --aggGEMM1--> bufA (z1) --GEMM2--> bufB (z2)
    for (int l = 0; l < NLAYER; ++l) {
        float* st1 = stats + (size_t)(2 * l) * NSLOT * 256;
        float* st2 = stats + (size_t)(2 * l + 1) * NSLOT * 256;
        if (l == 0)
            k_agg_gemm<false><<<ngemm, 256, 0, stream>>>(
                bufB, offs, deg, csrc, nullptr, nullptr, nullptr,
                Wt1, b1, (ushort*)bufA, st1, N_NODES, inv_n);
        else
            k_agg_gemm<true><<<ngemm, 256, 0, stream>>>(
                bufB, offs, deg, csrc,
                stats + (size_t)(2 * (l - 1) + 1) * NSLOT * 256,
                g2 + (l - 1) * D, be2 + (l - 1) * D,
                Wt1 + (size_t)l * D * D, b1 + l * D, (ushort*)bufA, st1, N_NODES, inv_n);
        k_gemm2<<<ngemm, 256, 0, stream>>>(
            (const ushort*)bufA, Wt2 + (size_t)l * D * D, b2 + l * D,
            st1, g1 + l * D, be1 + l * D, (ushort*)bufB, st2, N_NODES, inv_n);
    }
    // final BN2 (layer 2) params + apply, fp32 out
    k_bnparams<<<1, D, 0, stream>>>(stats + (size_t)5 * NSLOT * 256,
                                    g2 + 2 * D, be2 + 2 * D, scale2, shift2, inv_n);
    k_final<<<nfin, 256, 0, stream>>>(bufB, scale2, shift2, (float*)d_out, N_NODES * D / 4);
}

// Round 5
// 734.806 us; speedup vs baseline: 1.4655x; 1.4655x over previous
//
#include <hip/hip_runtime.h>

#define N_NODES 100000
#define N_EDGES 1600000
#define D 128
#define NLAYER 3
#define NSLOT 32

// bucket sort params
#define NBKT 98          // ceil(100000 / 1024) node-buckets of 1024
#define EPB 4096         // edges per block in phase A
#define BCAP 96          // LDS per-bucket capacity (mean ~42/block)

typedef __bf16 bf16x8 __attribute__((ext_vector_type(8)));
typedef float f32x4 __attribute__((ext_vector_type(4)));

__device__ inline ushort f2b(float f) {
    union { float f; unsigned u; } v; v.f = f;
    unsigned u = v.u;
    return (ushort)((u + 0x7FFFu + ((u >> 16) & 1u)) >> 16);  // RNE
}
__device__ inline float b2f_lo(unsigned u) {
    union { unsigned u; float f; } v; v.u = u << 16; return v.f;
}
__device__ inline float b2f_hi(unsigned u) {
    union { unsigned u; float f; } v; v.u = u & 0xFFFF0000u; return v.f;
}

// x fp32 -> packed bf16 (layer-0 agg input): halves layer-0 gather bytes
__global__ __launch_bounds__(256)
void k_x2b(const float* __restrict__ x, unsigned* __restrict__ out, int n4) {
    int i = blockIdx.x * 256 + threadIdx.x;  // float4 index
    if (i >= n4) return;
    float4 v = ((const float4*)x)[i];
    uint2 o;
    o.x = (unsigned)f2b(v.x) | ((unsigned)f2b(v.y) << 16);
    o.y = (unsigned)f2b(v.z) | ((unsigned)f2b(v.w) << 16);
    ((uint2*)out)[i] = o;
}

// ---------------------------------------------------------------- CSR build
__global__ void k_hist(const int* __restrict__ dst, int* __restrict__ deg, int e) {
    int i = blockIdx.x * blockDim.x + threadIdx.x;
    if (i < e) atomicAdd(&deg[dst[i]], 1);
}

__global__ void k_scan_partial(const int* __restrict__ deg, int* __restrict__ bsum, int n) {
    __shared__ int sd[256];
    int tid  = threadIdx.x;
    int base = blockIdx.x * 1024 + tid * 4;
    int s = 0;
    #pragma unroll
    for (int j = 0; j < 4; ++j) {
        int idx = base + j;
        if (idx < n) s += deg[idx];
    }
    sd[tid] = s;
    __syncthreads();
    for (int o = 128; o > 0; o >>= 1) {
        if (tid < o) sd[tid] += sd[tid + o];
        __syncthreads();
    }
    if (tid == 0) bsum[blockIdx.x] = sd[0];
}

__global__ void k_scan_top(int* __restrict__ bsum, int nb) {
    __shared__ int sd[128];
    int tid = threadIdx.x;
    int v = (tid < nb) ? bsum[tid] : 0;
    sd[tid] = v;
    __syncthreads();
    int tot = v;
    for (int o = 1; o < 128; o <<= 1) {
        int t = (tid >= o) ? sd[tid - o] : 0;
        __syncthreads();
        sd[tid] += t;
        __syncthreads();
    }
    if (tid < nb) bsum[tid] = sd[tid] - tot;  // exclusive
}

__global__ void k_scan_final(const int* __restrict__ deg, const int* __restrict__ bofs,
                             int* __restrict__ offs, int* __restrict__ cursor,
                             int* __restrict__ bcur, int n) {
    __shared__ int sd[256];
    int tid  = threadIdx.x;
    int base = blockIdx.x * 1024 + tid * 4;
    int v[4];
    int s = 0;
    #pragma unroll
    for (int j = 0; j < 4; ++j) {
        int idx = base + j;
        v[j] = (idx < n) ? deg[idx] : 0;
        s += v[j];
    }
    sd[tid] = s;
    __syncthreads();
    int own = s;
    for (int o = 1; o < 256; o <<= 1) {
        int t = (tid >= o) ? sd[tid - o] : 0;
        __syncthreads();
        sd[tid] += t;
        __syncthreads();
    }
    int excl = sd[tid] - own + bofs[blockIdx.x];
    #pragma unroll
    for (int j = 0; j < 4; ++j) {
        int idx = base + j;
        if (idx < n) {
            offs[idx] = excl; cursor[idx] = excl;
            if ((idx & 1023) == 0) bcur[idx >> 10] = excl;  // bucket region start
        }
        excl += v[j];
    }
}

// ---------------------------------------------------------------- bucketed edge sort
__global__ __launch_bounds__(256)
void k_bucket(const int* __restrict__ src, const int* __restrict__ dst,
              int* __restrict__ bcur, unsigned* __restrict__ staged, int e) {
    __shared__ unsigned lstage[NBKT * BCAP];
    __shared__ int lcur[NBKT];
    __shared__ int lbase[NBKT];
    int tid = threadIdx.x;
    for (int b = tid; b < NBKT; b += 256) lcur[b] = 0;
    __syncthreads();
    int base = blockIdx.x * EPB;
    for (int k = 0; k < EPB / 256; ++k) {
        int eid = base + k * 256 + tid;
        if (eid < e) {
            int d = dst[eid];
            int s = src[eid];
            int b = d >> 10;
            unsigned packed = ((unsigned)(d & 1023) << 17) | (unsigned)s;
            int p = atomicAdd(&lcur[b], 1);
            if (p < BCAP) {
                lstage[b * BCAP + p] = packed;
            } else {  // overflow fallback (statistically never: cap = 2.3x mean)
                int gp = atomicAdd(&bcur[b], 1);
                staged[gp] = packed;
            }
        }
    }
    __syncthreads();
    if (tid < NBKT) {
        int cnt = min(lcur[tid], BCAP);
        lbase[tid] = atomicAdd(&bcur[tid], cnt);
        lcur[tid] = cnt;
    }
    __syncthreads();
    int wave = tid >> 6, lane = tid & 63;
    for (int b = wave; b < NBKT; b += 4) {
        int cnt = lcur[b], gb = lbase[b];
        for (int j = lane; j < cnt; j += 64)
            staged[gb + j] = lstage[b * BCAP + j];
    }
}

__global__ __launch_bounds__(1024)
void k_place(const unsigned* __restrict__ staged, const int* __restrict__ offs,
             int* __restrict__ cursor, int* __restrict__ csrc) {
    int b = blockIdx.x;
    int start = offs[b << 10];
    int end = (b == NBKT - 1) ? N_EDGES : offs[(b + 1) << 10];
    int nodebase = b << 10;
    for (int i = start + blockIdx.y * 1024 + threadIdx.x; i < end; i += 2048) {
        unsigned p = staged[i];
        int s = (int)(p & 0x1FFFFu);
        int rel = (int)(p >> 17);
        int pos = atomicAdd(&cursor[nodebase + rel], 1);
        csrc[pos] = s;
    }
}

// ---------------------------------------------------------------- aggregation
// out[i,:] = bf16( f(h[i,:]) + sum_j f(h[src_j,:]) ),  f = AFF ? relu(v*sc+sh) : v.
// One wave per node (25000 blocks -> full gather TLP; do NOT fuse with GEMM).
template <bool AFF>
__device__ inline void acc8(float* a, uint4 u, const float* sc, const float* sh) {
    float v[8];
    v[0] = b2f_lo(u.x); v[1] = b2f_hi(u.x);
    v[2] = b2f_lo(u.y); v[3] = b2f_hi(u.y);
    v[4] = b2f_lo(u.z); v[5] = b2f_hi(u.z);
    v[6] = b2f_lo(u.w); v[7] = b2f_hi(u.w);
    #pragma unroll
    for (int j = 0; j < 8; ++j) {
        float t = v[j];
        if (AFF) {
            t = t * sc[j] + sh[j];
            t = t > 0.f ? t : 0.f;
        }
        a[j] += t;
    }
}

template <bool AFF>
__global__ __launch_bounds__(256)
void k_agg(const unsigned* __restrict__ h, const int* __restrict__ offs,
           const int* __restrict__ deg, const int* __restrict__ csrc,
           const float* __restrict__ sc_, const float* __restrict__ sh_,
           unsigned* __restrict__ out, int n) {
    int node = blockIdx.x * 4 + (threadIdx.x >> 6);
    if (node >= n) return;
    int lane = threadIdx.x & 63;
    int q  = lane >> 4;   // neighbor stream j === q (mod 4)
    int sl = lane & 15;   // covers uints 4sl..4sl+3 (cols 8sl..8sl+7)
    const uint4* hp = (const uint4*)h;
    float sc[8], sh[8];
    if (AFF) {
        #pragma unroll
        for (int j = 0; j < 8; ++j) { sc[j] = sc_[sl * 8 + j]; sh[j] = sh_[sl * 8 + j]; }
    }
    float a[8];
    #pragma unroll
    for (int j = 0; j < 8; ++j) a[j] = 0.f;
    if (q == 0) acc8<AFF>(a, hp[(size_t)node * 16 + sl], sc, sh);
    int s = offs[node], d = deg[node];
    for (int c = 0; c < d; c += 64) {
        int m = min(64, d - c);
        int myi = (lane < m) ? csrc[s + c + lane] : 0;
        int g4 = m >> 2;
        int g = 0;
        for (; g + 4 <= g4; g += 4) {
            int n0 = __shfl(myi, 4 * g + 0 + q);
            int n1 = __shfl(myi, 4 * g + 4 + q);
            int n2 = __shfl(myi, 4 * g + 8 + q);
            int n3 = __shfl(myi, 4 * g + 12 + q);
            uint4 u0 = hp[(size_t)n0 * 16 + sl];
            uint4 u1 = hp[(size_t)n1 * 16 + sl];
            uint4 u2 = hp[(size_t)n2 * 16 + sl];
            uint4 u3 = hp[(size_t)n3 * 16 + sl];
            acc8<AFF>(a, u0, sc, sh);
            acc8<AFF>(a, u1, sc, sh);
            acc8<AFF>(a, u2, sc, sh);
            acc8<AFF>(a, u3, sc, sh);
        }
        for (; g < g4; ++g) {
            int nb = __shfl(myi, 4 * g + q);
            acc8<AFF>(a, hp[(size_t)nb * 16 + sl], sc, sh);
        }
        int rem = m & 3;
        if (rem) {
            int j = 4 * g4 + q;
            int nb = __shfl(myi, j < m ? j : 0);  // convergent shfl
            if (q < rem) acc8<AFF>(a, hp[(size_t)nb * 16 + sl], sc, sh);
        }
    }
    #pragma unroll
    for (int j = 0; j < 8; ++j) {
        a[j] += __shfl_xor(a[j], 16);
        a[j] += __shfl_xor(a[j], 32);
    }
    if (q == 0) {
        uint4 o;
        o.x = (unsigned)f2b(a[0]) | ((unsigned)f2b(a[1]) << 16);
        o.y = (unsigned)f2b(a[2]) | ((unsigned)f2b(a[3]) << 16);
        o.z = (unsigned)f2b(a[4]) | ((unsigned)f2b(a[5]) << 16);
        o.w = (unsigned)f2b(a[6]) | ((unsigned)f2b(a[7]) << 16);
        ((uint4*)out)[(size_t)node * 16 + sl] = o;
    }
}

// ---------------------------------------------------------------- weight prep
// W fp32 [3][k=128][n=128] -> Wt bf16 [3][n=128][k=128]
__global__ void k_wprep(const float* __restrict__ W, ushort* __restrict__ Wt) {
    int m = blockIdx.y, nn = blockIdx.x, k = threadIdx.x;
    float v = W[(m * D + k) * D + nn];
    Wt[(m * D + nn) * D + k] = f2b(v);
}

// ---------------------------------------------------------------- MFMA GEMM
// AFF=false: C = A @ Wt + bias          (A raw bf16)
// AFF=true : C = relu(bn(A)) @ Wt + bias, bn params computed in prologue from
//            stats_in (removes k_bnparams launch from the critical path).
// Column stats of C accumulated: per-block LDS reduce -> 256 atomics/block
// into NSLOT=32 slots (was 1024 atomics into 8 slots: ~16x less contention).
__device__ inline bf16x8 affine_frag(uint4 raw, int kb,
                                     const float* __restrict__ sc,
                                     const float* __restrict__ sh) {
    unsigned u[4];
    u[0] = raw.x; u[1] = raw.y; u[2] = raw.z; u[3] = raw.w;
    bf16x8 r;
    #pragma unroll
    for (int p = 0; p < 4; ++p) {
        float lo = b2f_lo(u[p]) * sc[kb + 2 * p] + sh[kb + 2 * p];
        float hi = b2f_hi(u[p]) * sc[kb + 2 * p + 1] + sh[kb + 2 * p + 1];
        lo = lo > 0.f ? lo : 0.f;
        hi = hi > 0.f ? hi : 0.f;
        r[2 * p] = (__bf16)lo;
        r[2 * p + 1] = (__bf16)hi;
    }
    return r;
}

template <bool AFF>
__global__ __launch_bounds__(256)
void k_gemm(const ushort* __restrict__ A, const ushort* __restrict__ Wt,
            const float* __restrict__ bias,
            const float* __restrict__ stats_in, const float* __restrict__ gamma,
            const float* __restrict__ beta,
            ushort* __restrict__ C, float* __restrict__ stats_out,
            int n, float inv_n) {
    __shared__ ushort WtS[128 * 136];   // row stride 136 ushorts = 272 B
    __shared__ float redS[4][256];      // per-wave col stats staging
    __shared__ float sc_lds[128], sh_lds[128];

    int tid = threadIdx.x;

    // stage Wt (32 KB = 2048 uint4) coalesced
    const uint4* wsrc = (const uint4*)Wt;
    #pragma unroll
    for (int j = 0; j < 8; ++j) {
        int i = tid + j * 256;
        int r = i >> 4, s16 = i & 15;
        *(uint4*)&WtS[r * 136 + s16 * 8] = wsrc[i];
    }
    if (AFF && tid < 128) {
        float s = 0.f, qq = 0.f;
        for (int sl = 0; sl < NSLOT; ++sl) {
            s  += stats_in[sl * 256 + tid];
            qq += stats_in[sl * 256 + 128 + tid];
        }
        float mu  = s * inv_n;
        float var = qq * inv_n - mu * mu;
        var = var < 0.f ? 0.f : var;
        float rs = rsqrtf(var + 1e-5f);
        float sc = gamma[tid] * rs;
        sc_lds[tid] = sc;
        sh_lds[tid] = beta[tid] - mu * sc;
    }

    int wv   = tid >> 6;
    int lane = tid & 63;
    int m16  = lane & 15;
    int kq   = lane >> 4;
    int rowbase = blockIdx.x * 128 + wv * 32;

    // preload raw A bits before the barrier (overlaps Wt staging)
    uint4 zero4; zero4.x = zero4.y = zero4.z = zero4.w = 0u;
    uint4 raw0[4], raw1[4];
    #pragma unroll
    for (int ks = 0; ks < 4; ++ks) {
        int kb = ks * 32 + kq * 8;
        int r0 = rowbase + m16, r1 = rowbase + 16 + m16;
        raw0[ks] = (r0 < n) ? *(const uint4*)&A[(size_t)r0 * D + kb] : zero4;
        raw1[ks] = (r1 < n) ? *(const uint4*)&A[(size_t)r1 * D + kb] : zero4;
    }
    __syncthreads();

    bf16x8 a0[4], a1[4];
    #pragma unroll
    for (int ks = 0; ks < 4; ++ks) {
        int kb = ks * 32 + kq * 8;
        if (AFF) {
            a0[ks] = affine_frag(raw0[ks], kb, sc_lds, sh_lds);
            a1[ks] = affine_frag(raw1[ks], kb, sc_lds, sh_lds);
        } else {
            a0[ks] = *reinterpret_cast<bf16x8*>(&raw0[ks]);
            a1[ks] = *reinterpret_cast<bf16x8*>(&raw1[ks]);
        }
    }

    f32x4 acc0[8], acc1[8];
    #pragma unroll
    for (int t = 0; t < 8; ++t) {
        acc0[t] = (f32x4){0.f, 0.f, 0.f, 0.f};
        acc1[t] = (f32x4){0.f, 0.f, 0.f, 0.f};
    }

    #pragma unroll
    for (int ks = 0; ks < 4; ++ks) {
        #pragma unroll
        for (int t = 0; t < 8; ++t) {
            bf16x8 b = *(const bf16x8*)&WtS[(t * 16 + m16) * 136 + ks * 32 + kq * 8];
            acc0[t] = __builtin_amdgcn_mfma_f32_16x16x32_bf16(a0[ks], b, acc0[t], 0, 0, 0);
            acc1[t] = __builtin_amdgcn_mfma_f32_16x16x32_bf16(a1[ks], b, acc1[t], 0, 0, 0);
        }
    }

    // epilogue: bias, bf16 store, col stats -> LDS
    #pragma unroll
    for (int t = 0; t < 8; ++t) {
        int col = t * 16 + m16;
        float bz = bias[col];
        float s = 0.f, qv = 0.f;
        #pragma unroll
        for (int mt = 0; mt < 2; ++mt) {
            f32x4 v4 = mt ? acc1[t] : acc0[t];
            #pragma unroll
            for (int rr = 0; rr < 4; ++rr) {
                int row = rowbase + mt * 16 + kq * 4 + rr;
                if (row < n) {
                    float v = v4[rr] + bz;
                    C[(size_t)row * D + col] = f2b(v);
                    s += v; qv += v * v;
                }
            }
        }
        s += __shfl_xor(s, 16); qv += __shfl_xor(qv, 16);
        s += __shfl_xor(s, 32); qv += __shfl_xor(qv, 32);
        if (kq == 0) {
            redS[wv][col] = s;
            redS[wv][128 + col] = qv;
        }
    }
    __syncthreads();
    // block-level reduce: one atomic per stat-address per block
    int slot = blockIdx.x & (NSLOT - 1);
    float v = redS[0][tid & 255] + redS[1][tid & 255] + redS[2][tid & 255] + redS[3][tid & 255];
    atomicAdd(&stats_out[slot * 256 + (tid & 255)], v);
}

// ---------------------------------------------------------------- BN param fold
// (BN2 only: consumed by next layer's agg or the final apply)
__global__ void k_bnparams(const float* __restrict__ stats, const float* __restrict__ gamma,
                           const float* __restrict__ beta, float* __restrict__ scale,
                           float* __restrict__ shift, float inv_n) {
    int c = threadIdx.x;  // 128 threads
    float s = 0.f, q = 0.f;
    for (int sl = 0; sl < NSLOT; ++sl) {
        s += stats[sl * 256 + c];
        q += stats[sl * 256 + 128 + c];
    }
    float mu  = s * inv_n;
    float var = q * inv_n - mu * mu;
    var = var < 0.f ? 0.f : var;
    float rs = rsqrtf(var + 1e-5f);
    float sc = gamma[c] * rs;
    scale[c] = sc;
    shift[c] = beta[c] - mu * sc;
}

// ---------------------------------------------------------------- final BN apply (fp32 out)
__global__ __launch_bounds__(256)
void k_final(const unsigned* __restrict__ z, const float* __restrict__ scale,
             const float* __restrict__ shift, float* __restrict__ outf, int total2) {
    int i = blockIdx.x * 256 + threadIdx.x;  // index of uint2 = 4 bf16
    if (i >= total2) return;
    uint2 u = ((const uint2*)z)[i];
    int c = (i * 4) & (D - 1);
    float4 o;
    o.x = b2f_lo(u.x) * scale[c + 0] + shift[c + 0];
    o.y = b2f_hi(u.x) * scale[c + 1] + shift[c + 1];
    o.z = b2f_lo(u.y) * scale[c + 2] + shift[c + 2];
    o.w = b2f_hi(u.y) * scale[c + 3] + shift[c + 3];
    ((float4*)outf)[i] = o;
}

// ---------------------------------------------------------------- launch
extern "C" void kernel_launch(void* const* d_in, const int* in_sizes, int n_in,
                              void* d_out, int out_size, void* d_ws, size_t ws_size,
                              hipStream_t stream) {
    const float* x   = (const float*)d_in[0];
    const int*   ei  = (const int*)d_in[1];
    const float* W1  = (const float*)d_in[4];
    const float* b1  = (const float*)d_in[5];
    const float* g1  = (const float*)d_in[6];
    const float* be1 = (const float*)d_in[7];
    const float* W2  = (const float*)d_in[8];
    const float* b2  = (const float*)d_in[9];
    const float* g2  = (const float*)d_in[10];
    const float* be2 = (const float*)d_in[11];

    const int* srcI = ei;             // edge_index[0]
    const int* dstI = ei + N_EDGES;   // edge_index[1]

    // workspace layout (~61 MB)
    char* ws = (char*)d_ws;
    unsigned* bufA = (unsigned*)ws; ws += (size_t)N_NODES * 64 * 4 + 65536;
    unsigned* bufB = (unsigned*)ws; ws += (size_t)N_NODES * 64 * 4 + 65536;
    int* csrc    = (int*)ws;   ws += (size_t)N_EDGES * 4;
    int* deg     = (int*)ws;   ws += (size_t)N_NODES * 4;
    int* offs    = (int*)ws;   ws += (size_t)N_NODES * 4;
    int* cursor  = (int*)ws;   ws += (size_t)N_NODES * 4;
    int* bsum    = (int*)ws;   ws += 512;
    int* bcur    = (int*)ws;   ws += 512;
    ushort* Wt1  = (ushort*)ws; ws += 3 * D * D * 2;
    ushort* Wt2  = (ushort*)ws; ws += 3 * D * D * 2;
    float* stats = (float*)ws; ws += 6 * NSLOT * 256 * 4;  // 6 write-once regions
    float* scale2 = (float*)ws; ws += 512;
    float* shift2 = (float*)ws; ws += 512;

    // staging buffer for bucketed edge sort: reuse bufB (dead until x2b)
    unsigned* staged = bufB;

    // ---- weight prep (fp32 -> transposed bf16) ----
    k_wprep<<<dim3(D, 3), D, 0, stream>>>(W1, Wt1);
    k_wprep<<<dim3(D, 3), D, 0, stream>>>(W2, Wt2);

    // ---- CSR build ----
    hipMemsetAsync(deg, 0, (size_t)N_NODES * 4, stream);
    k_hist<<<(N_EDGES + 255) / 256, 256, 0, stream>>>(dstI, deg, N_EDGES);
    int nsb = (N_NODES + 1023) / 1024;  // 98
    k_scan_partial<<<nsb, 256, 0, stream>>>(deg, bsum, N_NODES);
    k_scan_top<<<1, 128, 0, stream>>>(bsum, nsb);
    k_scan_final<<<nsb, 256, 0, stream>>>(deg, bsum, offs, cursor, bcur, N_NODES);
    k_bucket<<<(N_EDGES + EPB - 1) / EPB, 256, 0, stream>>>(srcI, dstI, bcur, staged, N_EDGES);
    k_place<<<dim3(NBKT, 2), 1024, 0, stream>>>(staged, offs, cursor, csrc);

    // x -> bf16 into bufB (staged is dead now)
    k_x2b<<<(N_NODES * 32 + 255) / 256, 256, 0, stream>>>(x, bufB, N_NODES * 32);

    // zero all 6 write-once stats regions (per replay)
    hipMemsetAsync(stats, 0, (size_t)6 * NSLOT * 256 * 4, stream);

    const float inv_n = 1.0f / (float)N_NODES;
    int ngemm = (N_NODES + 127) / 128;  // 782
    int nagg  = (N_NODES + 3) / 4;
    int nfin  = (N_NODES * D / 4 + 255) / 256;

    // buffer ping-pong: cur = input to this layer's agg; alt = scratch
    unsigned* cur = bufB;
    unsigned* alt = bufA;

    for (int l = 0; l < NLAYER; ++l) {
        float* st1 = stats + (size_t)(2 * l) * NSLOT * 256;
        float* st2 = stats + (size_t)(2 * l + 1) * NSLOT * 256;
        // agg: cur -> alt.  l>0: BN2-apply+relu of previous layer fused in.
        if (l == 0)
            k_agg<false><<<nagg, 256, 0, stream>>>(cur, offs, deg, csrc,
                                                   nullptr, nullptr, alt, N_NODES);
        else
            k_agg<true><<<nagg, 256, 0, stream>>>(cur, offs, deg, csrc,
                                                  scale2, shift2, alt, N_NODES);
        // z1 = alt @ W1 + b1 -> cur (bf16), col stats -> st1
        k_gemm<false><<<ngemm, 256, 0, stream>>>(
            (const ushort*)alt, Wt1 + (size_t)l * D * D, b1 + l * D,
            nullptr, nullptr, nullptr, (ushort*)cur, st1, N_NODES, inv_n);
        // z2 = relu(bn1(z1)) @ W2 + b2 -> alt (bf16); BN1 from st1 in prologue
        k_gemm<true><<<ngemm, 256, 0, stream>>>(
            (const ushort*)cur, Wt2 + (size_t)l * D * D, b2 + l * D,
            st1, g1 + l * D, be1 + l * D, (ushort*)alt, st2, N_NODES, inv_n);
        // BN2 params for next agg (l<2) or final apply (l=2)
        k_bnparams<<<1, D, 0, stream>>>(st2, g2 + l * D, be2 + l * D,
                                        scale2, shift2, inv_n);
        // z2 lives in alt; it is the next layer's agg input
        unsigned* t = cur; cur = alt; alt = t;
    }
    // final BN2 apply (no relu), fp32 out
    k_final<<<nfin, 256, 0, stream>>>(cur, scale2, shift2, (float*)d_out, N_NODES * D / 4);
}